// Round 1
// baseline (365.282 us; speedup 1.0000x reference)
//
#include <hip/hip_runtime.h>
#include <hip/hip_bf16.h>

// B=4096, T=200, D=64, H=32 attention pooling with score MLP.
// score(b,t) = W2 . sigmoid( qa[b] + k_t @ Wk ),  Wk = W1b - W1c   (b2 softmax-invariant)
// qa[b][j]  = b1[j] + q_b @ (W1a + W1c)[:,j]
// Fixed-offset softmax: w_t = 2^((s_t-16)*log2e), |s| <= sum|W2| << 16; masked -> 0.
//
// R5 restructure: ONE wave per b loops all 13 row-tiles, accumulating the weighted
// key sum (acc[16] per lane) and denominator (dacc) in REGISTERS. No global atomics,
// no per-tile LDS staging, no finalize kernel, no num/den zero-init. Keys are
// double-buffered in registers (prefetch tile+1 while computing tile). 1024 blocks
// x 256 thr = 4096 waves = 4 waves/SIMD, all co-resident -> 64KB/CU of loads in
// flight, enough to saturate HBM. MFMA fragment layouts and score routing
// (shfl_xor reduce + ds_bpermute, verified R3/R4) are unchanged.

#define B 4096
#define T 200
#define D 64
#define H 32
#define LOG2E 1.44269504088896340736f
#define SOFF 16.0f
#define NTILE 13

typedef __attribute__((ext_vector_type(8))) short short8;   // 8 bf16 (MFMA A/B frag)
typedef __attribute__((ext_vector_type(4))) float f32x4;    // MFMA C/D frag

// ws float layout:
//   [0, 131072)            qa[B][32]
//   [131072, 132096)       wkf: 2048 bf16 B-fragments (1024 floats)

__global__ __launch_bounds__(256) void prep_kernel(
        const float* __restrict__ W1,     // [192,32]
        const float* __restrict__ b1,     // [32]
        const float* __restrict__ query,  // [B,1,D]
        float*       __restrict__ ws)
{
    int blk = blockIdx.x;
    int tid = threadIdx.x;
    if (blk < 512) {                       // qa
        int n = blk * 256 + tid;
        int b = n >> 5;
        int j = n & 31;
        const float* qb = query + (size_t)b * D;
        float acc = b1[j];
        #pragma unroll 8
        for (int i = 0; i < D; ++i)
            acc = fmaf(qb[i], W1[i * H + j] + W1[(128 + i) * H + j], acc);
        ws[n] = acc;
    } else {                               // wkf B-fragments (layout verified R3/R4)
        int m = (blk - 512) * 256 + tid;   // 0..2047
        int e  = m & 7;
        int l  = (m >> 3) & 63;
        int fs = m >> 9;
        int ntile = fs >> 1, kstep = fs & 1;
        int k = kstep * 32 + (l >> 4) * 8 + e;
        int j = ntile * 16 + (l & 15);
        float v = W1[(64 + k) * H + j] - W1[(128 + k) * H + j];
        __hip_bfloat16 hv = __float2bfloat16(v);
        reinterpret_cast<unsigned short*>(ws + 131072)[m] =
            __builtin_bit_cast(unsigned short, hv);
    }
}

__device__ __forceinline__ unsigned short bf16u(float x) {
    __hip_bfloat16 h = __float2bfloat16(x);
    return __builtin_bit_cast(unsigned short, h);
}

__global__ __launch_bounds__(256, 4) void attn_pool_kernel(
        const float* __restrict__ keys,   // [B,T,D] fp32
        const int*   __restrict__ mask,   // [B,T]
        const unsigned short* __restrict__ wkf, // 2048 bf16 B-fragments
        const float* __restrict__ qa_all, // [B,32]
        const float* __restrict__ W2,     // [32]
        float*       __restrict__ out)    // [B,1,D]
{
    const int tid  = threadIdx.x;
    const int wv   = tid >> 6;
    const int lane = tid & 63;
    const int quad = lane >> 4;
    const int l15  = lane & 15;

    const int b = blockIdx.x * 4 + wv;                  // one wave per batch row

    // Wk B-fragments (L2-broadcast) + per-b qa / W2 — loaded ONCE per wave now
    const short8* wf = reinterpret_cast<const short8*>(wkf);
    short8 bf0 = wf[0 * 64 + lane];
    short8 bf1 = wf[1 * 64 + lane];
    short8 bf2 = wf[2 * 64 + lane];
    short8 bf3 = wf[3 * 64 + lane];

    const float* qa = qa_all + (size_t)b * H;
    const float qa0 = qa[l15];
    const float qa1 = qa[16 + l15];
    const float w20 = W2[l15];
    const float w21 = W2[16 + l15];

    const float4* krow = reinterpret_cast<const float4*>(keys + (size_t)b * (T * D));
    const int*    mrow = mask + (size_t)b * T;
    const int ib = quad * 2;

    // register accumulators: lane covers cols {quad*8..+7} u {32+quad*8..+7},
    // rows t == l15 (mod 16) across the 13 tiles
    float acc[16];
    #pragma unroll
    for (int j = 0; j < 16; ++j) acc[j] = 0.0f;
    float dacc = 0.0f;

    // prefetch tile 0 (t = l15 < 200 always)
    float4 kA0 = krow[l15 * 16 + ib + 0];
    float4 kA1 = krow[l15 * 16 + ib + 1];
    float4 kA2 = krow[l15 * 16 + 8 + ib + 0];
    float4 kA3 = krow[l15 * 16 + 8 + ib + 1];
    int    mA  = mrow[l15];

    #pragma unroll
    for (int tile = 0; tile < NTILE; ++tile) {
        // prefetch next tile into the B register set
        float4 kB0 = kA0, kB1 = kA1, kB2 = kA2, kB3 = kA3;
        int    mB  = mA;
        if (tile + 1 < NTILE) {
            int tn  = (tile + 1) * 16 + l15;
            int trn = (tn < T) ? tn : (T - 1);          // clamp pad rows (weight forced 0)
            kB0 = krow[trn * 16 + ib + 0];
            kB1 = krow[trn * 16 + ib + 1];
            kB2 = krow[trn * 16 + 8 + ib + 0];
            kB3 = krow[trn * 16 + 8 + ib + 1];
            mB  = mrow[trn];
        }

        // bf16 A-fragments: A[m=l15][k=quad*8+e], second frag k+32
        short8 a0, a1;
        a0[0] = (short)bf16u(kA0.x); a0[1] = (short)bf16u(kA0.y);
        a0[2] = (short)bf16u(kA0.z); a0[3] = (short)bf16u(kA0.w);
        a0[4] = (short)bf16u(kA1.x); a0[5] = (short)bf16u(kA1.y);
        a0[6] = (short)bf16u(kA1.z); a0[7] = (short)bf16u(kA1.w);
        a1[0] = (short)bf16u(kA2.x); a1[1] = (short)bf16u(kA2.y);
        a1[2] = (short)bf16u(kA2.z); a1[3] = (short)bf16u(kA2.w);
        a1[4] = (short)bf16u(kA3.x); a1[5] = (short)bf16u(kA3.y);
        a1[6] = (short)bf16u(kA3.z); a1[7] = (short)bf16u(kA3.w);

        f32x4 c0 = {0.f, 0.f, 0.f, 0.f};
        f32x4 c1 = {0.f, 0.f, 0.f, 0.f};
        c0 = __builtin_amdgcn_mfma_f32_16x16x32_bf16(a0, bf0, c0, 0, 0, 0);
        c0 = __builtin_amdgcn_mfma_f32_16x16x32_bf16(a1, bf1, c0, 0, 0, 0);
        c1 = __builtin_amdgcn_mfma_f32_16x16x32_bf16(a0, bf2, c1, 0, 0, 0);
        c1 = __builtin_amdgcn_mfma_f32_16x16x32_bf16(a1, bf3, c1, 0, 0, 0);

        // sigmoid + W2 contraction; D layout: row t' = quad*4+r, col j = l15
        float p[4];
        #pragma unroll
        for (int r = 0; r < 4; ++r) {
            float x0 = c0[r] + qa0;
            float x1 = c1[r] + qa1;
            float s0 = __builtin_amdgcn_rcpf(1.0f + exp2f(-x0 * LOG2E));
            float s1 = __builtin_amdgcn_rcpf(1.0f + exp2f(-x1 * LOG2E));
            p[r] = fmaf(s0, w20, s1 * w21);
        }
        #pragma unroll
        for (int r = 0; r < 4; ++r) {
            #pragma unroll
            for (int off = 1; off <= 8; off <<= 1)
                p[r] += __shfl_xor(p[r], off, 64);      // reduce over 16 j-lanes
        }
        // route score[t'=l15] to the lane holding row t' (verified R4)
        const int addr = (l15 >> 2) << 6;
        int q0 = __builtin_amdgcn_ds_bpermute(addr, __builtin_bit_cast(int, p[0]));
        int q1 = __builtin_amdgcn_ds_bpermute(addr, __builtin_bit_cast(int, p[1]));
        int q2 = __builtin_amdgcn_ds_bpermute(addr, __builtin_bit_cast(int, p[2]));
        int q3 = __builtin_amdgcn_ds_bpermute(addr, __builtin_bit_cast(int, p[3]));
        const int rsel = l15 & 3;
        int s01 = (rsel & 1) ? q1 : q0;
        int s23 = (rsel & 1) ? q3 : q2;
        float st = __builtin_bit_cast(float, (rsel & 2) ? s23 : s01);

        const int t = tile * 16 + l15;
        const float w = ((t < T) && (mA != 0)) ? exp2f((st - SOFF) * LOG2E) : 0.0f;

        // register accumulation — replaces the old LDS staging + column sum + atomics
        acc[0]  = fmaf(w, kA0.x, acc[0]);  acc[1]  = fmaf(w, kA0.y, acc[1]);
        acc[2]  = fmaf(w, kA0.z, acc[2]);  acc[3]  = fmaf(w, kA0.w, acc[3]);
        acc[4]  = fmaf(w, kA1.x, acc[4]);  acc[5]  = fmaf(w, kA1.y, acc[5]);
        acc[6]  = fmaf(w, kA1.z, acc[6]);  acc[7]  = fmaf(w, kA1.w, acc[7]);
        acc[8]  = fmaf(w, kA2.x, acc[8]);  acc[9]  = fmaf(w, kA2.y, acc[9]);
        acc[10] = fmaf(w, kA2.z, acc[10]); acc[11] = fmaf(w, kA2.w, acc[11]);
        acc[12] = fmaf(w, kA3.x, acc[12]); acc[13] = fmaf(w, kA3.y, acc[13]);
        acc[14] = fmaf(w, kA3.z, acc[14]); acc[15] = fmaf(w, kA3.w, acc[15]);
        dacc += w;

        kA0 = kB0; kA1 = kB1; kA2 = kB2; kA3 = kB3; mA = mB;
    }

    // one-time cross-row reduction: sum over the 16 l15-lanes of each quad group
    #pragma unroll
    for (int j = 0; j < 16; ++j) {
        #pragma unroll
        for (int off = 1; off <= 8; off <<= 1)
            acc[j] += __shfl_xor(acc[j], off, 64);
    }
    #pragma unroll
    for (int off = 1; off <= 8; off <<= 1)
        dacc += __shfl_xor(dacc, off, 64);

    if (l15 == 0) {                                     // 4 writer lanes per wave
        float rw = __builtin_amdgcn_rcpf(dacc);
        float4 o0 = {acc[0]  * rw, acc[1]  * rw, acc[2]  * rw, acc[3]  * rw};
        float4 o1 = {acc[4]  * rw, acc[5]  * rw, acc[6]  * rw, acc[7]  * rw};
        float4 o2 = {acc[8]  * rw, acc[9]  * rw, acc[10] * rw, acc[11] * rw};
        float4 o3 = {acc[12] * rw, acc[13] * rw, acc[14] * rw, acc[15] * rw};
        float4* ob = reinterpret_cast<float4*>(out + (size_t)b * D);
        ob[ib + 0]     = o0;
        ob[ib + 1]     = o1;
        ob[8 + ib + 0] = o2;
        ob[8 + ib + 1] = o3;
    }
}

extern "C" void kernel_launch(void* const* d_in, const int* in_sizes, int n_in,
                              void* d_out, int out_size, void* d_ws, size_t ws_size,
                              hipStream_t stream) {
    const float* query = (const float*)d_in[0];
    const float* keys  = (const float*)d_in[1];
    const int*   mask  = (const int*)d_in[2];
    const float* W1    = (const float*)d_in[3];
    const float* b1    = (const float*)d_in[4];
    const float* W2    = (const float*)d_in[5];
    // d_in[6] = b2: softmax-invariant, unused.

    float* ws = (float*)d_ws;
    float* qa = ws;                                            // [B*32]
    unsigned short* wkf = (unsigned short*)(ws + 131072);      // 2048 bf16

    prep_kernel<<<520, 256, 0, stream>>>(W1, b1, query, ws);
    attn_pool_kernel<<<B / 4, 256, 0, stream>>>(keys, mask, wkf, qa, W2,
                                                (float*)d_out);
}

// Round 2
// 310.252 us; speedup vs baseline: 1.1774x; 1.1774x over previous
//
#include <hip/hip_runtime.h>
#include <hip/hip_bf16.h>

// B=4096, T=200, D=64, H=32 attention pooling with score MLP.
// score(b,t) = W2 . sigmoid( qa[b] + k_t @ Wk ),  Wk = W1b - W1c   (b2 softmax-invariant)
// qa[b][j]  = b1[j] + q_b @ (W1a + W1c)[:,j]
// Fixed-offset softmax: w_t = 2^((s_t-16)*log2e), |s| <= sum|W2| << 16; masked -> 0.
//
// R6: same structure as R5 (one wave per b, 13-tile register-accumulated loop) but
// WITHOUT the register cap that caused 142 MB of scratch spill in R5:
//   - __launch_bounds__(256) only (no min-waves clamp -> allocator free to ~128 VGPR)
//   - tile loop kept ROLLED (#pragma unroll 1): full unroll hoisted 13 tiles of
//     loads and blew the live set past the cap. Rolled + explicit 1-deep double
//     buffer is the intended ~100-reg live set.
// Evidence R5: VGPR_Count=64, WRITE_SIZE=143 MB (vs 1 MB output) = spill traffic.

#define B 4096
#define T 200
#define D 64
#define H 32
#define LOG2E 1.44269504088896340736f
#define SOFF 16.0f
#define NTILE 13

typedef __attribute__((ext_vector_type(8))) short short8;   // 8 bf16 (MFMA A/B frag)
typedef __attribute__((ext_vector_type(4))) float f32x4;    // MFMA C/D frag

// ws float layout:
//   [0, 131072)            qa[B][32]
//   [131072, 132096)       wkf: 2048 bf16 B-fragments (1024 floats)

__global__ __launch_bounds__(256) void prep_kernel(
        const float* __restrict__ W1,     // [192,32]
        const float* __restrict__ b1,     // [32]
        const float* __restrict__ query,  // [B,1,D]
        float*       __restrict__ ws)
{
    int blk = blockIdx.x;
    int tid = threadIdx.x;
    if (blk < 512) {                       // qa
        int n = blk * 256 + tid;
        int b = n >> 5;
        int j = n & 31;
        const float* qb = query + (size_t)b * D;
        float acc = b1[j];
        #pragma unroll 8
        for (int i = 0; i < D; ++i)
            acc = fmaf(qb[i], W1[i * H + j] + W1[(128 + i) * H + j], acc);
        ws[n] = acc;
    } else {                               // wkf B-fragments (layout verified R3/R4)
        int m = (blk - 512) * 256 + tid;   // 0..2047
        int e  = m & 7;
        int l  = (m >> 3) & 63;
        int fs = m >> 9;
        int ntile = fs >> 1, kstep = fs & 1;
        int k = kstep * 32 + (l >> 4) * 8 + e;
        int j = ntile * 16 + (l & 15);
        float v = W1[(64 + k) * H + j] - W1[(128 + k) * H + j];
        __hip_bfloat16 hv = __float2bfloat16(v);
        reinterpret_cast<unsigned short*>(ws + 131072)[m] =
            __builtin_bit_cast(unsigned short, hv);
    }
}

__device__ __forceinline__ unsigned short bf16u(float x) {
    __hip_bfloat16 h = __float2bfloat16(x);
    return __builtin_bit_cast(unsigned short, h);
}

__global__ __launch_bounds__(256) void attn_pool_kernel(
        const float* __restrict__ keys,   // [B,T,D] fp32
        const int*   __restrict__ mask,   // [B,T]
        const unsigned short* __restrict__ wkf, // 2048 bf16 B-fragments
        const float* __restrict__ qa_all, // [B,32]
        const float* __restrict__ W2,     // [32]
        float*       __restrict__ out)    // [B,1,D]
{
    const int tid  = threadIdx.x;
    const int wv   = tid >> 6;
    const int lane = tid & 63;
    const int quad = lane >> 4;
    const int l15  = lane & 15;

    const int b = blockIdx.x * 4 + wv;                  // one wave per batch row

    // Wk B-fragments (L2-broadcast) + per-b qa / W2 — loaded once per wave
    const short8* wf = reinterpret_cast<const short8*>(wkf);
    short8 bf0 = wf[0 * 64 + lane];
    short8 bf1 = wf[1 * 64 + lane];
    short8 bf2 = wf[2 * 64 + lane];
    short8 bf3 = wf[3 * 64 + lane];

    const float* qa = qa_all + (size_t)b * H;
    const float qa0 = qa[l15];
    const float qa1 = qa[16 + l15];
    const float w20 = W2[l15];
    const float w21 = W2[16 + l15];

    const float4* krow = reinterpret_cast<const float4*>(keys + (size_t)b * (T * D));
    const int*    mrow = mask + (size_t)b * T;
    const int ib = quad * 2;

    // register accumulators: lane covers cols {quad*8..+7} u {32+quad*8..+7},
    // rows t == l15 (mod 16) across the 13 tiles
    float acc[16];
    #pragma unroll
    for (int j = 0; j < 16; ++j) acc[j] = 0.0f;
    float dacc = 0.0f;

    // prefetch tile 0 (t = l15 < 200 always)
    float4 kA0 = krow[l15 * 16 + ib + 0];
    float4 kA1 = krow[l15 * 16 + ib + 1];
    float4 kA2 = krow[l15 * 16 + 8 + ib + 0];
    float4 kA3 = krow[l15 * 16 + 8 + ib + 1];
    int    mA  = mrow[l15];

    #pragma unroll 1
    for (int tile = 0; tile < NTILE; ++tile) {
        // prefetch next tile into the B register set
        float4 kB0 = kA0, kB1 = kA1, kB2 = kA2, kB3 = kA3;
        int    mB  = mA;
        if (tile + 1 < NTILE) {
            int tn  = (tile + 1) * 16 + l15;
            int trn = (tn < T) ? tn : (T - 1);          // clamp pad rows (weight forced 0)
            kB0 = krow[trn * 16 + ib + 0];
            kB1 = krow[trn * 16 + ib + 1];
            kB2 = krow[trn * 16 + 8 + ib + 0];
            kB3 = krow[trn * 16 + 8 + ib + 1];
            mB  = mrow[trn];
        }

        // bf16 A-fragments: A[m=l15][k=quad*8+e], second frag k+32
        short8 a0, a1;
        a0[0] = (short)bf16u(kA0.x); a0[1] = (short)bf16u(kA0.y);
        a0[2] = (short)bf16u(kA0.z); a0[3] = (short)bf16u(kA0.w);
        a0[4] = (short)bf16u(kA1.x); a0[5] = (short)bf16u(kA1.y);
        a0[6] = (short)bf16u(kA1.z); a0[7] = (short)bf16u(kA1.w);
        a1[0] = (short)bf16u(kA2.x); a1[1] = (short)bf16u(kA2.y);
        a1[2] = (short)bf16u(kA2.z); a1[3] = (short)bf16u(kA2.w);
        a1[4] = (short)bf16u(kA3.x); a1[5] = (short)bf16u(kA3.y);
        a1[6] = (short)bf16u(kA3.z); a1[7] = (short)bf16u(kA3.w);

        f32x4 c0 = {0.f, 0.f, 0.f, 0.f};
        f32x4 c1 = {0.f, 0.f, 0.f, 0.f};
        c0 = __builtin_amdgcn_mfma_f32_16x16x32_bf16(a0, bf0, c0, 0, 0, 0);
        c0 = __builtin_amdgcn_mfma_f32_16x16x32_bf16(a1, bf1, c0, 0, 0, 0);
        c1 = __builtin_amdgcn_mfma_f32_16x16x32_bf16(a0, bf2, c1, 0, 0, 0);
        c1 = __builtin_amdgcn_mfma_f32_16x16x32_bf16(a1, bf3, c1, 0, 0, 0);

        // sigmoid + W2 contraction; D layout: row t' = quad*4+r, col j = l15
        float p[4];
        #pragma unroll
        for (int r = 0; r < 4; ++r) {
            float x0 = c0[r] + qa0;
            float x1 = c1[r] + qa1;
            float s0 = __builtin_amdgcn_rcpf(1.0f + exp2f(-x0 * LOG2E));
            float s1 = __builtin_amdgcn_rcpf(1.0f + exp2f(-x1 * LOG2E));
            p[r] = fmaf(s0, w20, s1 * w21);
        }
        #pragma unroll
        for (int r = 0; r < 4; ++r) {
            #pragma unroll
            for (int off = 1; off <= 8; off <<= 1)
                p[r] += __shfl_xor(p[r], off, 64);      // reduce over 16 j-lanes
        }
        // route score[t'=l15] to the lane holding row t' (verified R4)
        const int addr = (l15 >> 2) << 6;
        int q0 = __builtin_amdgcn_ds_bpermute(addr, __builtin_bit_cast(int, p[0]));
        int q1 = __builtin_amdgcn_ds_bpermute(addr, __builtin_bit_cast(int, p[1]));
        int q2 = __builtin_amdgcn_ds_bpermute(addr, __builtin_bit_cast(int, p[2]));
        int q3 = __builtin_amdgcn_ds_bpermute(addr, __builtin_bit_cast(int, p[3]));
        const int rsel = l15 & 3;
        int s01 = (rsel & 1) ? q1 : q0;
        int s23 = (rsel & 1) ? q3 : q2;
        float st = __builtin_bit_cast(float, (rsel & 2) ? s23 : s01);

        const int t = tile * 16 + l15;
        const float w = ((t < T) && (mA != 0)) ? exp2f((st - SOFF) * LOG2E) : 0.0f;

        // register accumulation
        acc[0]  = fmaf(w, kA0.x, acc[0]);  acc[1]  = fmaf(w, kA0.y, acc[1]);
        acc[2]  = fmaf(w, kA0.z, acc[2]);  acc[3]  = fmaf(w, kA0.w, acc[3]);
        acc[4]  = fmaf(w, kA1.x, acc[4]);  acc[5]  = fmaf(w, kA1.y, acc[5]);
        acc[6]  = fmaf(w, kA1.z, acc[6]);  acc[7]  = fmaf(w, kA1.w, acc[7]);
        acc[8]  = fmaf(w, kA2.x, acc[8]);  acc[9]  = fmaf(w, kA2.y, acc[9]);
        acc[10] = fmaf(w, kA2.z, acc[10]); acc[11] = fmaf(w, kA2.w, acc[11]);
        acc[12] = fmaf(w, kA3.x, acc[12]); acc[13] = fmaf(w, kA3.y, acc[13]);
        acc[14] = fmaf(w, kA3.z, acc[14]); acc[15] = fmaf(w, kA3.w, acc[15]);
        dacc += w;

        kA0 = kB0; kA1 = kB1; kA2 = kB2; kA3 = kB3; mA = mB;
    }

    // one-time cross-row reduction: sum over the 16 l15-lanes of each quad group
    #pragma unroll
    for (int j = 0; j < 16; ++j) {
        #pragma unroll
        for (int off = 1; off <= 8; off <<= 1)
            acc[j] += __shfl_xor(acc[j], off, 64);
    }
    #pragma unroll
    for (int off = 1; off <= 8; off <<= 1)
        dacc += __shfl_xor(dacc, off, 64);

    if (l15 == 0) {                                     // 4 writer lanes per wave
        float rw = __builtin_amdgcn_rcpf(dacc);
        float4 o0 = {acc[0]  * rw, acc[1]  * rw, acc[2]  * rw, acc[3]  * rw};
        float4 o1 = {acc[4]  * rw, acc[5]  * rw, acc[6]  * rw, acc[7]  * rw};
        float4 o2 = {acc[8]  * rw, acc[9]  * rw, acc[10] * rw, acc[11] * rw};
        float4 o3 = {acc[12] * rw, acc[13] * rw, acc[14] * rw, acc[15] * rw};
        float4* ob = reinterpret_cast<float4*>(out + (size_t)b * D);
        ob[ib + 0]     = o0;
        ob[ib + 1]     = o1;
        ob[8 + ib + 0] = o2;
        ob[8 + ib + 1] = o3;
    }
}

extern "C" void kernel_launch(void* const* d_in, const int* in_sizes, int n_in,
                              void* d_out, int out_size, void* d_ws, size_t ws_size,
                              hipStream_t stream) {
    const float* query = (const float*)d_in[0];
    const float* keys  = (const float*)d_in[1];
    const int*   mask  = (const int*)d_in[2];
    const float* W1    = (const float*)d_in[3];
    const float* b1    = (const float*)d_in[4];
    const float* W2    = (const float*)d_in[5];
    // d_in[6] = b2: softmax-invariant, unused.

    float* ws = (float*)d_ws;
    float* qa = ws;                                            // [B*32]
    unsigned short* wkf = (unsigned short*)(ws + 131072);      // 2048 bf16

    prep_kernel<<<520, 256, 0, stream>>>(W1, b1, query, ws);
    attn_pool_kernel<<<B / 4, 256, 0, stream>>>(keys, mask, wkf, qa, W2,
                                                (float*)d_out);
}

// Round 3
// 303.792 us; speedup vs baseline: 1.2024x; 1.0213x over previous
//
#include <hip/hip_runtime.h>
#include <hip/hip_bf16.h>

// B=4096, T=200, D=64, H=32 attention pooling with score MLP.
// score(b,t) = W2 . sigmoid( qa[b] + k_t @ Wk ),  Wk = W1b - W1c   (b2 softmax-invariant)
// qa[b][j]  = b1[j] + q_b @ wsum[:,j],  wsum = W1a + W1c  (precomputed f32)
// Fixed-offset softmax: w_t = 2^((s_t-16)*log2e); masked -> 0.
//
// R7: R6 was latency-stalled (9 GB/s/CU with nothing saturated): 4096 serial
// 13-round waves, one generation. This round:
//  - 2 waves per b (tiles 0-6 / 7-12): 8192 waves, serial rounds halved,
//    partials combined via 2KB LDS + one __syncthreads at block end.
//  - qa computed IN-WAVE (f32, wsum table + LDS-broadcast query row), prep
//    shrinks to 16 blocks (wsum + wkf) -> one launch gap and the 512-block
//    qa pass removed.
// Per-tile MFMA + shuffle/bpermute score path is byte-identical to R6 (verified).

#define B 4096
#define T 200
#define D 64
#define H 32
#define LOG2E 1.44269504088896340736f
#define SOFF 16.0f
#define NTILE 13

typedef __attribute__((ext_vector_type(8))) short short8;   // 8 bf16 (MFMA A/B frag)
typedef __attribute__((ext_vector_type(4))) float f32x4;    // MFMA C/D frag

// ws float layout:
//   [0, 2048)       wsum[64][32] = W1a + W1c   (f32)
//   [2048, 3072)    wkf: 2048 bf16 B-fragments (1024 floats)

__global__ __launch_bounds__(256) void prep_kernel(
        const float* __restrict__ W1,     // [192,32]
        float*       __restrict__ ws)
{
    int n = blockIdx.x * 256 + threadIdx.x;
    if (blockIdx.x < 8) {                  // wsum = W1a + W1c
        int k = n >> 5;
        int j = n & 31;
        ws[n] = W1[k * H + j] + W1[(128 + k) * H + j];
    } else {                               // wkf B-fragments (layout verified R3/R4)
        int m = n - 2048;                  // 0..2047
        int e  = m & 7;
        int l  = (m >> 3) & 63;
        int fs = m >> 9;
        int ntile = fs >> 1, kstep = fs & 1;
        int k = kstep * 32 + (l >> 4) * 8 + e;
        int j = ntile * 16 + (l & 15);
        float v = W1[(64 + k) * H + j] - W1[(128 + k) * H + j];
        __hip_bfloat16 hv = __float2bfloat16(v);
        reinterpret_cast<unsigned short*>(ws + 2048)[m] =
            __builtin_bit_cast(unsigned short, hv);
    }
}

__device__ __forceinline__ unsigned short bf16u(float x) {
    __hip_bfloat16 h = __float2bfloat16(x);
    return __builtin_bit_cast(unsigned short, h);
}

__global__ __launch_bounds__(256) void attn_pool_kernel(
        const float* __restrict__ keys,   // [B,T,D] fp32
        const int*   __restrict__ mask,   // [B,T]
        const unsigned short* __restrict__ wkf, // 2048 bf16 B-fragments
        const float* __restrict__ wsum,   // [64][32] f32
        const float* __restrict__ b1,     // [32]
        const float* __restrict__ W2,     // [32]
        const float* __restrict__ query,  // [B,1,D]
        float*       __restrict__ out)    // [B,1,D]
{
    __shared__ float qsh[4][64];
    __shared__ float part[4][68];         // [wave][64 cols + den], 16B-aligned rows

    const int tid  = threadIdx.x;
    const int wv   = tid >> 6;
    const int lane = tid & 63;
    const int quad = lane >> 4;
    const int l15  = lane & 15;

    const int b    = blockIdx.x * 2 + (wv >> 1);        // 2 waves per batch row
    const int half = wv & 1;                            // tile range selector

    // ---- qa[b][0..31] computed in-wave, f32 (replaces the old qa prep pass) ----
    qsh[wv][lane] = query[(size_t)b * D + lane];        // stage query row
    const int jq = lane & 31;
    const int kh = lane >> 5;                           // k-half per lane group
    float qac0 = kh ? 0.0f : b1[jq];
    float qac1 = 0.0f;
    #pragma unroll
    for (int k0 = 0; k0 < 32; k0 += 2) {
        int k = kh * 32 + k0;
        qac0 = fmaf(qsh[wv][k],     wsum[k * H + jq],       qac0);
        qac1 = fmaf(qsh[wv][k + 1], wsum[(k + 1) * H + jq], qac1);
    }
    float qac = qac0 + qac1;
    qac += __shfl_xor(qac, 32, 64);                     // combine k-halves
    const float qa0 = __shfl(qac, l15, 64);             // qa[l15]
    const float qa1 = __shfl(qac, 16 + l15, 64);        // qa[16+l15]

    // ---- Wk B-fragments (L2-broadcast) + W2 ----
    const short8* wf = reinterpret_cast<const short8*>(wkf);
    short8 bf0 = wf[0 * 64 + lane];
    short8 bf1 = wf[1 * 64 + lane];
    short8 bf2 = wf[2 * 64 + lane];
    short8 bf3 = wf[3 * 64 + lane];
    const float w20 = W2[l15];
    const float w21 = W2[16 + l15];

    const float4* krow = reinterpret_cast<const float4*>(keys + (size_t)b * (T * D));
    const int*    mrow = mask + (size_t)b * T;
    const int ib = quad * 2;

    // register accumulators: lane covers cols {quad*8..+7} u {32+quad*8..+7}
    float acc[16];
    #pragma unroll
    for (int j = 0; j < 16; ++j) acc[j] = 0.0f;
    float dacc = 0.0f;

    const int t0  = half * 7;                           // tiles [t0, t0+ntl)
    const int ntl = half ? 6 : 7;

    // prefetch first tile (t = t0*16 + l15 <= 127 < T, no clamp needed)
    float4 kA0 = krow[(t0 * 16 + l15) * 16 + ib + 0];
    float4 kA1 = krow[(t0 * 16 + l15) * 16 + ib + 1];
    float4 kA2 = krow[(t0 * 16 + l15) * 16 + 8 + ib + 0];
    float4 kA3 = krow[(t0 * 16 + l15) * 16 + 8 + ib + 1];
    int    mA  = mrow[t0 * 16 + l15];

    #pragma unroll 1
    for (int it = 0; it < ntl; ++it) {
        const int tile = t0 + it;
        // prefetch next tile into the B register set
        float4 kB0 = kA0, kB1 = kA1, kB2 = kA2, kB3 = kA3;
        int    mB  = mA;
        if (it + 1 < ntl) {
            int tn  = (tile + 1) * 16 + l15;
            int trn = (tn < T) ? tn : (T - 1);          // clamp pad rows (weight forced 0)
            kB0 = krow[trn * 16 + ib + 0];
            kB1 = krow[trn * 16 + ib + 1];
            kB2 = krow[trn * 16 + 8 + ib + 0];
            kB3 = krow[trn * 16 + 8 + ib + 1];
            mB  = mrow[trn];
        }

        // bf16 A-fragments: A[m=l15][k=quad*8+e], second frag k+32
        short8 a0, a1;
        a0[0] = (short)bf16u(kA0.x); a0[1] = (short)bf16u(kA0.y);
        a0[2] = (short)bf16u(kA0.z); a0[3] = (short)bf16u(kA0.w);
        a0[4] = (short)bf16u(kA1.x); a0[5] = (short)bf16u(kA1.y);
        a0[6] = (short)bf16u(kA1.z); a0[7] = (short)bf16u(kA1.w);
        a1[0] = (short)bf16u(kA2.x); a1[1] = (short)bf16u(kA2.y);
        a1[2] = (short)bf16u(kA2.z); a1[3] = (short)bf16u(kA2.w);
        a1[4] = (short)bf16u(kA3.x); a1[5] = (short)bf16u(kA3.y);
        a1[6] = (short)bf16u(kA3.z); a1[7] = (short)bf16u(kA3.w);

        f32x4 c0 = {0.f, 0.f, 0.f, 0.f};
        f32x4 c1 = {0.f, 0.f, 0.f, 0.f};
        c0 = __builtin_amdgcn_mfma_f32_16x16x32_bf16(a0, bf0, c0, 0, 0, 0);
        c0 = __builtin_amdgcn_mfma_f32_16x16x32_bf16(a1, bf1, c0, 0, 0, 0);
        c1 = __builtin_amdgcn_mfma_f32_16x16x32_bf16(a0, bf2, c1, 0, 0, 0);
        c1 = __builtin_amdgcn_mfma_f32_16x16x32_bf16(a1, bf3, c1, 0, 0, 0);

        // sigmoid + W2 contraction; D layout: row t' = quad*4+r, col j = l15
        float p[4];
        #pragma unroll
        for (int r = 0; r < 4; ++r) {
            float x0 = c0[r] + qa0;
            float x1 = c1[r] + qa1;
            float s0 = __builtin_amdgcn_rcpf(1.0f + exp2f(-x0 * LOG2E));
            float s1 = __builtin_amdgcn_rcpf(1.0f + exp2f(-x1 * LOG2E));
            p[r] = fmaf(s0, w20, s1 * w21);
        }
        #pragma unroll
        for (int r = 0; r < 4; ++r) {
            #pragma unroll
            for (int off = 1; off <= 8; off <<= 1)
                p[r] += __shfl_xor(p[r], off, 64);      // reduce over 16 j-lanes
        }
        // route score[t'=l15] to the lane holding row t' (verified R4)
        const int addr = (l15 >> 2) << 6;
        int q0 = __builtin_amdgcn_ds_bpermute(addr, __builtin_bit_cast(int, p[0]));
        int q1 = __builtin_amdgcn_ds_bpermute(addr, __builtin_bit_cast(int, p[1]));
        int q2 = __builtin_amdgcn_ds_bpermute(addr, __builtin_bit_cast(int, p[2]));
        int q3 = __builtin_amdgcn_ds_bpermute(addr, __builtin_bit_cast(int, p[3]));
        const int rsel = l15 & 3;
        int s01 = (rsel & 1) ? q1 : q0;
        int s23 = (rsel & 1) ? q3 : q2;
        float st = __builtin_bit_cast(float, (rsel & 2) ? s23 : s01);

        const int t = tile * 16 + l15;
        const float w = ((t < T) && (mA != 0)) ? exp2f((st - SOFF) * LOG2E) : 0.0f;

        // register accumulation
        acc[0]  = fmaf(w, kA0.x, acc[0]);  acc[1]  = fmaf(w, kA0.y, acc[1]);
        acc[2]  = fmaf(w, kA0.z, acc[2]);  acc[3]  = fmaf(w, kA0.w, acc[3]);
        acc[4]  = fmaf(w, kA1.x, acc[4]);  acc[5]  = fmaf(w, kA1.y, acc[5]);
        acc[6]  = fmaf(w, kA1.z, acc[6]);  acc[7]  = fmaf(w, kA1.w, acc[7]);
        acc[8]  = fmaf(w, kA2.x, acc[8]);  acc[9]  = fmaf(w, kA2.y, acc[9]);
        acc[10] = fmaf(w, kA2.z, acc[10]); acc[11] = fmaf(w, kA2.w, acc[11]);
        acc[12] = fmaf(w, kA3.x, acc[12]); acc[13] = fmaf(w, kA3.y, acc[13]);
        acc[14] = fmaf(w, kA3.z, acc[14]); acc[15] = fmaf(w, kA3.w, acc[15]);
        dacc += w;

        kA0 = kB0; kA1 = kB1; kA2 = kB2; kA3 = kB3; mA = mB;
    }

    // intra-wave reduction over the 16 t-lanes
    #pragma unroll
    for (int j = 0; j < 16; ++j) {
        #pragma unroll
        for (int off = 1; off <= 8; off <<= 1)
            acc[j] += __shfl_xor(acc[j], off, 64);
    }
    #pragma unroll
    for (int off = 1; off <= 8; off <<= 1)
        dacc += __shfl_xor(dacc, off, 64);

    // write this wave's partial (cols per quad) to LDS
    if (l15 == 0) {
        float4 o0 = {acc[0],  acc[1],  acc[2],  acc[3]};
        float4 o1 = {acc[4],  acc[5],  acc[6],  acc[7]};
        float4 o2 = {acc[8],  acc[9],  acc[10], acc[11]};
        float4 o3 = {acc[12], acc[13], acc[14], acc[15]};
        *reinterpret_cast<float4*>(&part[wv][quad * 8 + 0])      = o0;
        *reinterpret_cast<float4*>(&part[wv][quad * 8 + 4])      = o1;
        *reinterpret_cast<float4*>(&part[wv][32 + quad * 8 + 0]) = o2;
        *reinterpret_cast<float4*>(&part[wv][32 + quad * 8 + 4]) = o3;
    }
    if (lane == 0) part[wv][64] = dacc;
    __syncthreads();

    // combine wave pairs and write out (128 threads: 2 b-rows x 64 cols)
    if (tid < 128) {
        int bb = tid >> 6;
        int d  = tid & 63;
        float s  = part[bb * 2][d]  + part[bb * 2 + 1][d];
        float dn = part[bb * 2][64] + part[bb * 2 + 1][64];
        out[((size_t)blockIdx.x * 2 + bb) * D + d] = s * __builtin_amdgcn_rcpf(dn);
    }
}

extern "C" void kernel_launch(void* const* d_in, const int* in_sizes, int n_in,
                              void* d_out, int out_size, void* d_ws, size_t ws_size,
                              hipStream_t stream) {
    const float* query = (const float*)d_in[0];
    const float* keys  = (const float*)d_in[1];
    const int*   mask  = (const int*)d_in[2];
    const float* W1    = (const float*)d_in[3];
    const float* b1    = (const float*)d_in[4];
    const float* W2    = (const float*)d_in[5];
    // d_in[6] = b2: softmax-invariant, unused.

    float* ws = (float*)d_ws;
    float* wsum = ws;                                          // [64*32]
    unsigned short* wkf = (unsigned short*)(ws + 2048);        // 2048 bf16

    prep_kernel<<<16, 256, 0, stream>>>(W1, ws);
    attn_pool_kernel<<<B / 2, 256, 0, stream>>>(keys, mask, wkf, wsum, b1, W2,
                                                query, (float*)d_out);
}

// Round 4
// 301.320 us; speedup vs baseline: 1.2123x; 1.0082x over previous
//
#include <hip/hip_runtime.h>
#include <hip/hip_bf16.h>

// B=4096, T=200, D=64, H=32 attention pooling with score MLP.
// score(b,t) = W2 . sigmoid( qa[b] + k_t @ Wk ),  Wk = W1b - W1c   (b2 softmax-invariant)
// qa[b][j]  = b1[j] + q_b @ wsum[:,j],  wsum = W1a + W1c  (precomputed f32)
// Fixed-offset softmax: w_t = 2^((s_t-16)*log2e); masked -> 0.
//
// R8: R0/R2/R3 (3 different concurrency structures) all plateau at ~2.4 TB/s read
// BW with every pipe <10% busy -> shared bottleneck = DRAM-stream thrash from
// ~4096 concurrent independent 51KB streams scattered across XCDs. This round:
//  - ONE BLOCK PER b: the 4 waves share one key row, tiles INTERLEAVED
//    (wave wv takes tiles wv, wv+4, wv+8[, 12]) so the block's in-flight
//    prefetches are 4 consecutive tiles = 16KB contiguous -> ~1 forward stream
//    per block, 4 streams/CU (was 16).
//  - bijective XCD swizzle b=(bid%8)*512+bid/8: each XCD owns a contiguous
//    26MB key window.
//  - 4-way LDS partial combine (extension of R7's 2-way; one __syncthreads).
// Per-tile MFMA + shuffle/bpermute score path byte-identical to R6/R7 (verified).

#define B 4096
#define T 200
#define D 64
#define H 32
#define LOG2E 1.44269504088896340736f
#define SOFF 16.0f
#define NTILE 13

typedef __attribute__((ext_vector_type(8))) short short8;   // 8 bf16 (MFMA A/B frag)
typedef __attribute__((ext_vector_type(4))) float f32x4;    // MFMA C/D frag

// ws float layout:
//   [0, 2048)       wsum[64][32] = W1a + W1c   (f32)
//   [2048, 3072)    wkf: 2048 bf16 B-fragments (1024 floats)

__global__ __launch_bounds__(256) void prep_kernel(
        const float* __restrict__ W1,     // [192,32]
        float*       __restrict__ ws)
{
    int n = blockIdx.x * 256 + threadIdx.x;
    if (blockIdx.x < 8) {                  // wsum = W1a + W1c
        int k = n >> 5;
        int j = n & 31;
        ws[n] = W1[k * H + j] + W1[(128 + k) * H + j];
    } else {                               // wkf B-fragments (layout verified R3/R4)
        int m = n - 2048;                  // 0..2047
        int e  = m & 7;
        int l  = (m >> 3) & 63;
        int fs = m >> 9;
        int ntile = fs >> 1, kstep = fs & 1;
        int k = kstep * 32 + (l >> 4) * 8 + e;
        int j = ntile * 16 + (l & 15);
        float v = W1[(64 + k) * H + j] - W1[(128 + k) * H + j];
        __hip_bfloat16 hv = __float2bfloat16(v);
        reinterpret_cast<unsigned short*>(ws + 2048)[m] =
            __builtin_bit_cast(unsigned short, hv);
    }
}

__device__ __forceinline__ unsigned short bf16u(float x) {
    __hip_bfloat16 h = __float2bfloat16(x);
    return __builtin_bit_cast(unsigned short, h);
}

__global__ __launch_bounds__(256) void attn_pool_kernel(
        const float* __restrict__ keys,   // [B,T,D] fp32
        const int*   __restrict__ mask,   // [B,T]
        const unsigned short* __restrict__ wkf, // 2048 bf16 B-fragments
        const float* __restrict__ wsum,   // [64][32] f32
        const float* __restrict__ b1,     // [32]
        const float* __restrict__ W2,     // [32]
        const float* __restrict__ query,  // [B,1,D]
        float*       __restrict__ out)    // [B,1,D]
{
    __shared__ float qsh[4][64];
    __shared__ float part[4][68];         // [wave][64 cols + den]

    const int tid  = threadIdx.x;
    const int wv   = tid >> 6;
    const int lane = tid & 63;
    const int quad = lane >> 4;
    const int l15  = lane & 15;

    // bijective XCD swizzle: each XCD owns a contiguous 512-row key window
    const int b = (blockIdx.x & 7) * (B / 8) + (blockIdx.x >> 3);

    // ---- qa[b][0..31] computed in-wave, f32 ----
    qsh[wv][lane] = query[(size_t)b * D + lane];        // stage query row
    const int jq = lane & 31;
    const int kh = lane >> 5;                           // k-half per lane group
    float qac0 = kh ? 0.0f : b1[jq];
    float qac1 = 0.0f;
    #pragma unroll
    for (int k0 = 0; k0 < 32; k0 += 2) {
        int k = kh * 32 + k0;
        qac0 = fmaf(qsh[wv][k],     wsum[k * H + jq],       qac0);
        qac1 = fmaf(qsh[wv][k + 1], wsum[(k + 1) * H + jq], qac1);
    }
    float qac = qac0 + qac1;
    qac += __shfl_xor(qac, 32, 64);                     // combine k-halves
    const float qa0 = __shfl(qac, l15, 64);             // qa[l15]
    const float qa1 = __shfl(qac, 16 + l15, 64);        // qa[16+l15]

    // ---- Wk B-fragments (L2-broadcast) + W2 ----
    const short8* wf = reinterpret_cast<const short8*>(wkf);
    short8 bf0 = wf[0 * 64 + lane];
    short8 bf1 = wf[1 * 64 + lane];
    short8 bf2 = wf[2 * 64 + lane];
    short8 bf3 = wf[3 * 64 + lane];
    const float w20 = W2[l15];
    const float w21 = W2[16 + l15];

    const float4* krow = reinterpret_cast<const float4*>(keys + (size_t)b * (T * D));
    const int*    mrow = mask + (size_t)b * T;
    const int ib = quad * 2;

    // register accumulators: lane covers cols {quad*8..+7} u {32+quad*8..+7}
    float acc[16];
    #pragma unroll
    for (int j = 0; j < 16; ++j) acc[j] = 0.0f;
    float dacc = 0.0f;

    // interleaved tile assignment: wave wv takes tiles wv, wv+4, wv+8 (+12 for wv=0)
    const int ntl = (wv == 0) ? 4 : 3;

    // prefetch first tile (t = wv*16 + l15 <= 63 < T, no clamp needed)
    float4 kA0 = krow[(wv * 16 + l15) * 16 + ib + 0];
    float4 kA1 = krow[(wv * 16 + l15) * 16 + ib + 1];
    float4 kA2 = krow[(wv * 16 + l15) * 16 + 8 + ib + 0];
    float4 kA3 = krow[(wv * 16 + l15) * 16 + 8 + ib + 1];
    int    mA  = mrow[wv * 16 + l15];

    #pragma unroll 1
    for (int it = 0; it < ntl; ++it) {
        const int tile = wv + it * 4;
        // prefetch next tile into the B register set
        float4 kB0 = kA0, kB1 = kA1, kB2 = kA2, kB3 = kA3;
        int    mB  = mA;
        if (it + 1 < ntl) {
            int tn  = (wv + (it + 1) * 4) * 16 + l15;
            int trn = (tn < T) ? tn : (T - 1);          // clamp pad rows (weight forced 0)
            kB0 = krow[trn * 16 + ib + 0];
            kB1 = krow[trn * 16 + ib + 1];
            kB2 = krow[trn * 16 + 8 + ib + 0];
            kB3 = krow[trn * 16 + 8 + ib + 1];
            mB  = mrow[trn];
        }

        // bf16 A-fragments: A[m=l15][k=quad*8+e], second frag k+32
        short8 a0, a1;
        a0[0] = (short)bf16u(kA0.x); a0[1] = (short)bf16u(kA0.y);
        a0[2] = (short)bf16u(kA0.z); a0[3] = (short)bf16u(kA0.w);
        a0[4] = (short)bf16u(kA1.x); a0[5] = (short)bf16u(kA1.y);
        a0[6] = (short)bf16u(kA1.z); a0[7] = (short)bf16u(kA1.w);
        a1[0] = (short)bf16u(kA2.x); a1[1] = (short)bf16u(kA2.y);
        a1[2] = (short)bf16u(kA2.z); a1[3] = (short)bf16u(kA2.w);
        a1[4] = (short)bf16u(kA3.x); a1[5] = (short)bf16u(kA3.y);
        a1[6] = (short)bf16u(kA3.z); a1[7] = (short)bf16u(kA3.w);

        f32x4 c0 = {0.f, 0.f, 0.f, 0.f};
        f32x4 c1 = {0.f, 0.f, 0.f, 0.f};
        c0 = __builtin_amdgcn_mfma_f32_16x16x32_bf16(a0, bf0, c0, 0, 0, 0);
        c0 = __builtin_amdgcn_mfma_f32_16x16x32_bf16(a1, bf1, c0, 0, 0, 0);
        c1 = __builtin_amdgcn_mfma_f32_16x16x32_bf16(a0, bf2, c1, 0, 0, 0);
        c1 = __builtin_amdgcn_mfma_f32_16x16x32_bf16(a1, bf3, c1, 0, 0, 0);

        // sigmoid + W2 contraction; D layout: row t' = quad*4+r, col j = l15
        float p[4];
        #pragma unroll
        for (int r = 0; r < 4; ++r) {
            float x0 = c0[r] + qa0;
            float x1 = c1[r] + qa1;
            float s0 = __builtin_amdgcn_rcpf(1.0f + exp2f(-x0 * LOG2E));
            float s1 = __builtin_amdgcn_rcpf(1.0f + exp2f(-x1 * LOG2E));
            p[r] = fmaf(s0, w20, s1 * w21);
        }
        #pragma unroll
        for (int r = 0; r < 4; ++r) {
            #pragma unroll
            for (int off = 1; off <= 8; off <<= 1)
                p[r] += __shfl_xor(p[r], off, 64);      // reduce over 16 j-lanes
        }
        // route score[t'=l15] to the lane holding row t' (verified R4)
        const int addr = (l15 >> 2) << 6;
        int q0 = __builtin_amdgcn_ds_bpermute(addr, __builtin_bit_cast(int, p[0]));
        int q1 = __builtin_amdgcn_ds_bpermute(addr, __builtin_bit_cast(int, p[1]));
        int q2 = __builtin_amdgcn_ds_bpermute(addr, __builtin_bit_cast(int, p[2]));
        int q3 = __builtin_amdgcn_ds_bpermute(addr, __builtin_bit_cast(int, p[3]));
        const int rsel = l15 & 3;
        int s01 = (rsel & 1) ? q1 : q0;
        int s23 = (rsel & 1) ? q3 : q2;
        float st = __builtin_bit_cast(float, (rsel & 2) ? s23 : s01);

        const int t = tile * 16 + l15;
        const float w = ((t < T) && (mA != 0)) ? exp2f((st - SOFF) * LOG2E) : 0.0f;

        // register accumulation
        acc[0]  = fmaf(w, kA0.x, acc[0]);  acc[1]  = fmaf(w, kA0.y, acc[1]);
        acc[2]  = fmaf(w, kA0.z, acc[2]);  acc[3]  = fmaf(w, kA0.w, acc[3]);
        acc[4]  = fmaf(w, kA1.x, acc[4]);  acc[5]  = fmaf(w, kA1.y, acc[5]);
        acc[6]  = fmaf(w, kA1.z, acc[6]);  acc[7]  = fmaf(w, kA1.w, acc[7]);
        acc[8]  = fmaf(w, kA2.x, acc[8]);  acc[9]  = fmaf(w, kA2.y, acc[9]);
        acc[10] = fmaf(w, kA2.z, acc[10]); acc[11] = fmaf(w, kA2.w, acc[11]);
        acc[12] = fmaf(w, kA3.x, acc[12]); acc[13] = fmaf(w, kA3.y, acc[13]);
        acc[14] = fmaf(w, kA3.z, acc[14]); acc[15] = fmaf(w, kA3.w, acc[15]);
        dacc += w;

        kA0 = kB0; kA1 = kB1; kA2 = kB2; kA3 = kB3; mA = mB;
    }

    // intra-wave reduction over the 16 t-lanes
    #pragma unroll
    for (int j = 0; j < 16; ++j) {
        #pragma unroll
        for (int off = 1; off <= 8; off <<= 1)
            acc[j] += __shfl_xor(acc[j], off, 64);
    }
    #pragma unroll
    for (int off = 1; off <= 8; off <<= 1)
        dacc += __shfl_xor(dacc, off, 64);

    // write this wave's partial (cols per quad) to LDS
    if (l15 == 0) {
        float4 o0 = {acc[0],  acc[1],  acc[2],  acc[3]};
        float4 o1 = {acc[4],  acc[5],  acc[6],  acc[7]};
        float4 o2 = {acc[8],  acc[9],  acc[10], acc[11]};
        float4 o3 = {acc[12], acc[13], acc[14], acc[15]};
        *reinterpret_cast<float4*>(&part[wv][quad * 8 + 0])      = o0;
        *reinterpret_cast<float4*>(&part[wv][quad * 8 + 4])      = o1;
        *reinterpret_cast<float4*>(&part[wv][32 + quad * 8 + 0]) = o2;
        *reinterpret_cast<float4*>(&part[wv][32 + quad * 8 + 4]) = o3;
    }
    if (lane == 0) part[wv][64] = dacc;
    __syncthreads();

    // combine the 4 wave partials and write out (64 threads: 64 cols)
    if (tid < 64) {
        float s  = (part[0][tid] + part[1][tid]) + (part[2][tid] + part[3][tid]);
        float dn = (part[0][64]  + part[1][64])  + (part[2][64]  + part[3][64]);
        out[(size_t)b * D + tid] = s * __builtin_amdgcn_rcpf(dn);
    }
}

extern "C" void kernel_launch(void* const* d_in, const int* in_sizes, int n_in,
                              void* d_out, int out_size, void* d_ws, size_t ws_size,
                              hipStream_t stream) {
    const float* query = (const float*)d_in[0];
    const float* keys  = (const float*)d_in[1];
    const int*   mask  = (const int*)d_in[2];
    const float* W1    = (const float*)d_in[3];
    const float* b1    = (const float*)d_in[4];
    const float* W2    = (const float*)d_in[5];
    // d_in[6] = b2: softmax-invariant, unused.

    float* ws = (float*)d_ws;
    float* wsum = ws;                                          // [64*32]
    unsigned short* wkf = (unsigned short*)(ws + 2048);        // 2048 bf16

    prep_kernel<<<16, 256, 0, stream>>>(W1, ws);
    attn_pool_kernel<<<B, 256, 0, stream>>>(keys, mask, wkf, wsum, b1, W2,
                                            query, (float*)d_out);
}

// Round 5
// 299.828 us; speedup vs baseline: 1.2183x; 1.0050x over previous
//
#include <hip/hip_runtime.h>
#include <hip/hip_bf16.h>

// B=4096, T=200, D=64, H=32 attention pooling with score MLP.
// score(b,t) = W2 . sigmoid( qa[b] + k_t @ Wk ),  Wk = W1b - W1c   (b2 softmax-invariant)
// qa[b][j]  = b1[j] + q_b @ wsum[:,j],  wsum = W1a + W1c  (precomputed f32)
// Fixed-offset softmax: w_t = 2^((s_t-16)*log2e); masked -> 0.
//
// R9: R0-R8 ledger: read BW pinned at ~2.6 TB/s across ALL concurrency topologies,
// all pipes <10% busy -> queue-limited. Remaining suspects: per-wave outstanding-
// bytes starvation (1-deep prefetch = 4KB/wave, drained every iteration) or DRAM
// row-hit inefficiency of a 31%-dense resident window. Both fixed by the same
// lever: 2-DEEP register prefetch (3-buffer rotation, unconditional clamped
// loads) -> 8KB/wave outstanding, 63%-dense window. Also: swizzle removed
// (contiguous dispatch = contiguous frontier). Everything else = R8.
// Per-tile MFMA + shuffle/bpermute score path byte-identical to R6-R8 (verified).

#define B 4096
#define T 200
#define D 64
#define H 32
#define LOG2E 1.44269504088896340736f
#define SOFF 16.0f
#define NTILE 13

typedef __attribute__((ext_vector_type(8))) short short8;   // 8 bf16 (MFMA A/B frag)
typedef __attribute__((ext_vector_type(4))) float f32x4;    // MFMA C/D frag

// ws float layout:
//   [0, 2048)       wsum[64][32] = W1a + W1c   (f32)
//   [2048, 3072)    wkf: 2048 bf16 B-fragments (1024 floats)

__global__ __launch_bounds__(256) void prep_kernel(
        const float* __restrict__ W1,     // [192,32]
        float*       __restrict__ ws)
{
    int n = blockIdx.x * 256 + threadIdx.x;
    if (blockIdx.x < 8) {                  // wsum = W1a + W1c
        int k = n >> 5;
        int j = n & 31;
        ws[n] = W1[k * H + j] + W1[(128 + k) * H + j];
    } else {                               // wkf B-fragments (layout verified R3/R4)
        int m = n - 2048;                  // 0..2047
        int e  = m & 7;
        int l  = (m >> 3) & 63;
        int fs = m >> 9;
        int ntile = fs >> 1, kstep = fs & 1;
        int k = kstep * 32 + (l >> 4) * 8 + e;
        int j = ntile * 16 + (l & 15);
        float v = W1[(64 + k) * H + j] - W1[(128 + k) * H + j];
        __hip_bfloat16 hv = __float2bfloat16(v);
        reinterpret_cast<unsigned short*>(ws + 2048)[m] =
            __builtin_bit_cast(unsigned short, hv);
    }
}

__device__ __forceinline__ unsigned short bf16u(float x) {
    __hip_bfloat16 h = __float2bfloat16(x);
    return __builtin_bit_cast(unsigned short, h);
}

__global__ __launch_bounds__(256) void attn_pool_kernel(
        const float* __restrict__ keys,   // [B,T,D] fp32
        const int*   __restrict__ mask,   // [B,T]
        const unsigned short* __restrict__ wkf, // 2048 bf16 B-fragments
        const float* __restrict__ wsum,   // [64][32] f32
        const float* __restrict__ b1,     // [32]
        const float* __restrict__ W2,     // [32]
        const float* __restrict__ query,  // [B,1,D]
        float*       __restrict__ out)    // [B,1,D]
{
    __shared__ float qsh[4][64];
    __shared__ float part[4][68];         // [wave][64 cols + den]

    const int tid  = threadIdx.x;
    const int wv   = tid >> 6;
    const int lane = tid & 63;
    const int quad = lane >> 4;
    const int l15  = lane & 15;

    const int b = blockIdx.x;             // contiguous dispatch = contiguous frontier

    // ---- qa[b][0..31] computed in-wave, f32 ----
    qsh[wv][lane] = query[(size_t)b * D + lane];        // stage query row
    const int jq = lane & 31;
    const int kh = lane >> 5;                           // k-half per lane group
    float qac0 = kh ? 0.0f : b1[jq];
    float qac1 = 0.0f;
    #pragma unroll
    for (int k0 = 0; k0 < 32; k0 += 2) {
        int k = kh * 32 + k0;
        qac0 = fmaf(qsh[wv][k],     wsum[k * H + jq],       qac0);
        qac1 = fmaf(qsh[wv][k + 1], wsum[(k + 1) * H + jq], qac1);
    }
    float qac = qac0 + qac1;
    qac += __shfl_xor(qac, 32, 64);                     // combine k-halves
    const float qa0 = __shfl(qac, l15, 64);             // qa[l15]
    const float qa1 = __shfl(qac, 16 + l15, 64);        // qa[16+l15]

    // ---- Wk B-fragments (L2-broadcast) + W2 ----
    const short8* wf = reinterpret_cast<const short8*>(wkf);
    short8 bf0 = wf[0 * 64 + lane];
    short8 bf1 = wf[1 * 64 + lane];
    short8 bf2 = wf[2 * 64 + lane];
    short8 bf3 = wf[3 * 64 + lane];
    const float w20 = W2[l15];
    const float w21 = W2[16 + l15];

    const float4* krow = reinterpret_cast<const float4*>(keys + (size_t)b * (T * D));
    const int*    mrow = mask + (size_t)b * T;
    const int ib = quad * 2;

    // register accumulators: lane covers cols {quad*8..+7} u {32+quad*8..+7}
    float acc[16];
    #pragma unroll
    for (int j = 0; j < 16; ++j) acc[j] = 0.0f;
    float dacc = 0.0f;

    // interleaved tile assignment: wave wv takes tiles wv, wv+4, wv+8 (+12 for wv=0)
    const int ntl = (wv == 0) ? 4 : 3;

    // 2-deep prefetch: tiles wv (A) and wv+4 (B) in flight before the loop.
    // t(A) = wv*16+l15 <= 63, t(B) = (wv+4)*16+l15 <= 127 -> both < T, no clamp.
    float4 kA0 = krow[(wv * 16 + l15) * 16 + ib + 0];
    float4 kA1 = krow[(wv * 16 + l15) * 16 + ib + 1];
    float4 kA2 = krow[(wv * 16 + l15) * 16 + 8 + ib + 0];
    float4 kA3 = krow[(wv * 16 + l15) * 16 + 8 + ib + 1];
    int    mA  = mrow[wv * 16 + l15];
    float4 kB0 = krow[((wv + 4) * 16 + l15) * 16 + ib + 0];
    float4 kB1 = krow[((wv + 4) * 16 + l15) * 16 + ib + 1];
    float4 kB2 = krow[((wv + 4) * 16 + l15) * 16 + 8 + ib + 0];
    float4 kB3 = krow[((wv + 4) * 16 + l15) * 16 + 8 + ib + 1];
    int    mB  = mrow[(wv + 4) * 16 + l15];

    #pragma unroll 1
    for (int it = 0; it < ntl; ++it) {
        const int tile = wv + it * 4;

        // issue prefetch for tile+2 FIRST, unconditional, address-clamped
        // (last 2 iterations re-read row T-1: 256B, L2-hit, harmless)
        int tn  = (wv + (it + 2) * 4) * 16 + l15;
        int trn = (tn < T) ? tn : (T - 1);
        float4 kC0 = krow[trn * 16 + ib + 0];
        float4 kC1 = krow[trn * 16 + ib + 1];
        float4 kC2 = krow[trn * 16 + 8 + ib + 0];
        float4 kC3 = krow[trn * 16 + 8 + ib + 1];
        int    mC  = mrow[trn];

        // bf16 A-fragments: A[m=l15][k=quad*8+e], second frag k+32
        short8 a0, a1;
        a0[0] = (short)bf16u(kA0.x); a0[1] = (short)bf16u(kA0.y);
        a0[2] = (short)bf16u(kA0.z); a0[3] = (short)bf16u(kA0.w);
        a0[4] = (short)bf16u(kA1.x); a0[5] = (short)bf16u(kA1.y);
        a0[6] = (short)bf16u(kA1.z); a0[7] = (short)bf16u(kA1.w);
        a1[0] = (short)bf16u(kA2.x); a1[1] = (short)bf16u(kA2.y);
        a1[2] = (short)bf16u(kA2.z); a1[3] = (short)bf16u(kA2.w);
        a1[4] = (short)bf16u(kA3.x); a1[5] = (short)bf16u(kA3.y);
        a1[6] = (short)bf16u(kA3.z); a1[7] = (short)bf16u(kA3.w);

        f32x4 c0 = {0.f, 0.f, 0.f, 0.f};
        f32x4 c1 = {0.f, 0.f, 0.f, 0.f};
        c0 = __builtin_amdgcn_mfma_f32_16x16x32_bf16(a0, bf0, c0, 0, 0, 0);
        c0 = __builtin_amdgcn_mfma_f32_16x16x32_bf16(a1, bf1, c0, 0, 0, 0);
        c1 = __builtin_amdgcn_mfma_f32_16x16x32_bf16(a0, bf2, c1, 0, 0, 0);
        c1 = __builtin_amdgcn_mfma_f32_16x16x32_bf16(a1, bf3, c1, 0, 0, 0);

        // sigmoid + W2 contraction; D layout: row t' = quad*4+r, col j = l15
        float p[4];
        #pragma unroll
        for (int r = 0; r < 4; ++r) {
            float x0 = c0[r] + qa0;
            float x1 = c1[r] + qa1;
            float s0 = __builtin_amdgcn_rcpf(1.0f + exp2f(-x0 * LOG2E));
            float s1 = __builtin_amdgcn_rcpf(1.0f + exp2f(-x1 * LOG2E));
            p[r] = fmaf(s0, w20, s1 * w21);
        }
        #pragma unroll
        for (int r = 0; r < 4; ++r) {
            #pragma unroll
            for (int off = 1; off <= 8; off <<= 1)
                p[r] += __shfl_xor(p[r], off, 64);      // reduce over 16 j-lanes
        }
        // route score[t'=l15] to the lane holding row t' (verified R4)
        const int addr = (l15 >> 2) << 6;
        int q0 = __builtin_amdgcn_ds_bpermute(addr, __builtin_bit_cast(int, p[0]));
        int q1 = __builtin_amdgcn_ds_bpermute(addr, __builtin_bit_cast(int, p[1]));
        int q2 = __builtin_amdgcn_ds_bpermute(addr, __builtin_bit_cast(int, p[2]));
        int q3 = __builtin_amdgcn_ds_bpermute(addr, __builtin_bit_cast(int, p[3]));
        const int rsel = l15 & 3;
        int s01 = (rsel & 1) ? q1 : q0;
        int s23 = (rsel & 1) ? q3 : q2;
        float st = __builtin_bit_cast(float, (rsel & 2) ? s23 : s01);

        const int t = tile * 16 + l15;
        const float w = ((t < T) && (mA != 0)) ? exp2f((st - SOFF) * LOG2E) : 0.0f;

        // register accumulation
        acc[0]  = fmaf(w, kA0.x, acc[0]);  acc[1]  = fmaf(w, kA0.y, acc[1]);
        acc[2]  = fmaf(w, kA0.z, acc[2]);  acc[3]  = fmaf(w, kA0.w, acc[3]);
        acc[4]  = fmaf(w, kA1.x, acc[4]);  acc[5]  = fmaf(w, kA1.y, acc[5]);
        acc[6]  = fmaf(w, kA1.z, acc[6]);  acc[7]  = fmaf(w, kA1.w, acc[7]);
        acc[8]  = fmaf(w, kA2.x, acc[8]);  acc[9]  = fmaf(w, kA2.y, acc[9]);
        acc[10] = fmaf(w, kA2.z, acc[10]); acc[11] = fmaf(w, kA2.w, acc[11]);
        acc[12] = fmaf(w, kA3.x, acc[12]); acc[13] = fmaf(w, kA3.y, acc[13]);
        acc[14] = fmaf(w, kA3.z, acc[14]); acc[15] = fmaf(w, kA3.w, acc[15]);
        dacc += w;

        // rotate the 3-buffer pipeline
        kA0 = kB0; kA1 = kB1; kA2 = kB2; kA3 = kB3; mA = mB;
        kB0 = kC0; kB1 = kC1; kB2 = kC2; kB3 = kC3; mB = mC;
    }

    // intra-wave reduction over the 16 t-lanes
    #pragma unroll
    for (int j = 0; j < 16; ++j) {
        #pragma unroll
        for (int off = 1; off <= 8; off <<= 1)
            acc[j] += __shfl_xor(acc[j], off, 64);
    }
    #pragma unroll
    for (int off = 1; off <= 8; off <<= 1)
        dacc += __shfl_xor(dacc, off, 64);

    // write this wave's partial (cols per quad) to LDS
    if (l15 == 0) {
        float4 o0 = {acc[0],  acc[1],  acc[2],  acc[3]};
        float4 o1 = {acc[4],  acc[5],  acc[6],  acc[7]};
        float4 o2 = {acc[8],  acc[9],  acc[10], acc[11]};
        float4 o3 = {acc[12], acc[13], acc[14], acc[15]};
        *reinterpret_cast<float4*>(&part[wv][quad * 8 + 0])      = o0;
        *reinterpret_cast<float4*>(&part[wv][quad * 8 + 4])      = o1;
        *reinterpret_cast<float4*>(&part[wv][32 + quad * 8 + 0]) = o2;
        *reinterpret_cast<float4*>(&part[wv][32 + quad * 8 + 4]) = o3;
    }
    if (lane == 0) part[wv][64] = dacc;
    __syncthreads();

    // combine the 4 wave partials and write out (64 threads: 64 cols)
    if (tid < 64) {
        float s  = (part[0][tid] + part[1][tid]) + (part[2][tid] + part[3][tid]);
        float dn = (part[0][64]  + part[1][64])  + (part[2][64]  + part[3][64]);
        out[(size_t)b * D + tid] = s * __builtin_amdgcn_rcpf(dn);
    }
}

extern "C" void kernel_launch(void* const* d_in, const int* in_sizes, int n_in,
                              void* d_out, int out_size, void* d_ws, size_t ws_size,
                              hipStream_t stream) {
    const float* query = (const float*)d_in[0];
    const float* keys  = (const float*)d_in[1];
    const int*   mask  = (const int*)d_in[2];
    const float* W1    = (const float*)d_in[3];
    const float* b1    = (const float*)d_in[4];
    const float* W2    = (const float*)d_in[5];
    // d_in[6] = b2: softmax-invariant, unused.

    float* ws = (float*)d_ws;
    float* wsum = ws;                                          // [64*32]
    unsigned short* wkf = (unsigned short*)(ws + 2048);        // 2048 bf16

    prep_kernel<<<16, 256, 0, stream>>>(W1, ws);
    attn_pool_kernel<<<B, 256, 0, stream>>>(keys, mask, wkf, wsum, b1, W2,
                                            query, (float*)d_out);
}